// Round 6
// baseline (104.194 us; speedup 1.0000x reference)
//
#include <hip/hip_runtime.h>

// Two-scalar fused loss over 8192x4096 f32 arrays:
//   out[0] = sum( (|y|>=mu) + (0<|y|<mu)*|y|/mu ) / 8192   [== min(|y|/mu,1)]
//   out[1] = sum( (y_echo/22.8 - f)^2 ) / 8192
// Memory-bound streaming reduction: 3 arrays x 134MB read, 8B written.
// Round 5 lesson: nt loads removed L3 fill traffic (135->88us, FETCH
// unchanged). Now at 4.6 TB/s total. Panels start 64KB-aligned => channel
// phase aliasing across 2048 blocks. Fix: grid-stride (grid collectively
// sweeps contiguous 8MB regions => uniform channel load) + 4x unroll for
// more lines in flight per wave.

#define ECHO_SCALE 22.8f
#define N_ROWS 8192.0f

typedef float fx4 __attribute__((ext_vector_type(4)));

__global__ void init_out_kernel(float* out) {
    if (threadIdx.x < 2) out[threadIdx.x] = 0.0f;
}

__device__ __forceinline__ fx4 ldnt(const fx4* p) {
    return __builtin_nontemporal_load(p);
}

__device__ __forceinline__ void consume(const fx4& vy, const fx4& ve,
                                        const fx4& vf, float inv_mu,
                                        float inv_echo, float& s0, float& s1) {
    s0 += fminf(fabsf(vy.x) * inv_mu, 1.0f);
    s0 += fminf(fabsf(vy.y) * inv_mu, 1.0f);
    s0 += fminf(fabsf(vy.z) * inv_mu, 1.0f);
    s0 += fminf(fabsf(vy.w) * inv_mu, 1.0f);
    float dx = ve.x * inv_echo - vf.x;
    float dy = ve.y * inv_echo - vf.y;
    float dz = ve.z * inv_echo - vf.z;
    float dw = ve.w * inv_echo - vf.w;
    s1 += dx * dx;
    s1 += dy * dy;
    s1 += dz * dz;
    s1 += dw * dw;
}

__global__ __launch_bounds__(256) void loss_kernel(
    const fx4* __restrict__ y,
    const fx4* __restrict__ ye,
    const fx4* __restrict__ f,
    const float* __restrict__ mu_ptr,
    float* __restrict__ out,
    long long n4)
{
    const float mu = mu_ptr[0];
    const float inv_mu = 1.0f / mu;
    const float inv_echo = 1.0f / ECHO_SCALE;

    float s0a = 0.0f, s0b = 0.0f, s0c = 0.0f, s0d = 0.0f;
    float s1a = 0.0f, s1b = 0.0f, s1c = 0.0f, s1d = 0.0f;

    const long long idx = (long long)blockIdx.x * blockDim.x + threadIdx.x;
    const long long stride = (long long)gridDim.x * blockDim.x;

    long long i = idx;
    for (; i + 3 * stride < n4; i += 4 * stride) {
        // 12 non-temporal loads in flight before any consume
        fx4 vy0 = ldnt(&y[i]);
        fx4 vy1 = ldnt(&y[i + stride]);
        fx4 vy2 = ldnt(&y[i + 2 * stride]);
        fx4 vy3 = ldnt(&y[i + 3 * stride]);
        fx4 ve0 = ldnt(&ye[i]);
        fx4 ve1 = ldnt(&ye[i + stride]);
        fx4 ve2 = ldnt(&ye[i + 2 * stride]);
        fx4 ve3 = ldnt(&ye[i + 3 * stride]);
        fx4 vf0 = ldnt(&f[i]);
        fx4 vf1 = ldnt(&f[i + stride]);
        fx4 vf2 = ldnt(&f[i + 2 * stride]);
        fx4 vf3 = ldnt(&f[i + 3 * stride]);

        consume(vy0, ve0, vf0, inv_mu, inv_echo, s0a, s1a);
        consume(vy1, ve1, vf1, inv_mu, inv_echo, s0b, s1b);
        consume(vy2, ve2, vf2, inv_mu, inv_echo, s0c, s1c);
        consume(vy3, ve3, vf3, inv_mu, inv_echo, s0d, s1d);
    }
    for (; i < n4; i += stride) {
        fx4 vy = ldnt(&y[i]);
        fx4 ve = ldnt(&ye[i]);
        fx4 vf = ldnt(&f[i]);
        consume(vy, ve, vf, inv_mu, inv_echo, s0a, s1a);
    }

    float s0 = (s0a + s0b) + (s0c + s0d);
    float s1 = (s1a + s1b) + (s1c + s1d);

    // wave-64 butterfly reduce
    #pragma unroll
    for (int off = 32; off > 0; off >>= 1) {
        s0 += __shfl_down(s0, off, 64);
        s1 += __shfl_down(s1, off, 64);
    }

    __shared__ float l0[4];
    __shared__ float l1[4];
    const int wave = threadIdx.x >> 6;
    const int lane = threadIdx.x & 63;
    if (lane == 0) { l0[wave] = s0; l1[wave] = s1; }
    __syncthreads();

    if (threadIdx.x == 0) {
        float t0 = 0.0f, t1 = 0.0f;
        #pragma unroll
        for (int w = 0; w < 4; ++w) { t0 += l0[w]; t1 += l1[w]; }
        atomicAdd(&out[0], t0 * (1.0f / N_ROWS));
        atomicAdd(&out[1], t1 * (1.0f / N_ROWS));
    }
}

extern "C" void kernel_launch(void* const* d_in, const int* in_sizes, int n_in,
                              void* d_out, int out_size, void* d_ws, size_t ws_size,
                              hipStream_t stream) {
    const fx4* y  = (const fx4*)d_in[0];
    const fx4* ye = (const fx4*)d_in[1];
    const fx4* f  = (const fx4*)d_in[2];
    const float* mu  = (const float*)d_in[3];
    float* out = (float*)d_out;

    const long long n  = (long long)in_sizes[0];  // 8192*4096, divisible by 4
    const long long n4 = n / 4;

    init_out_kernel<<<1, 64, 0, stream>>>(out);

    const int block = 256;
    int grid = 2048;  // 256 CUs x 8 blocks (max resident); grid-stride rest
    long long needed = (n4 + block - 1) / block;
    if (needed < grid) grid = (int)needed;

    loss_kernel<<<grid, block, 0, stream>>>(y, ye, f, mu, out, n4);
}

// Round 7
// 87.459 us; speedup vs baseline: 1.1913x; 1.1913x over previous
//
#include <hip/hip_runtime.h>

// Two-scalar fused loss over 8192x4096 f32 arrays:
//   out[0] = sum( min(|y|/mu, 1) ) / 8192
//   out[1] = sum( (y_echo/22.8 - f)^2 ) / 8192
// Memory-bound pure-read reduction: 3 arrays x 134MB, 8B written.
// Round 5: panels + nt loads = 88us (4.6 TB/s aggregate). Round 6: grid-stride
// regressed (98us) -> panels win. This round: split block roles so each block
// streams 1 array (y: s0-blocks) or 2 arrays (ye,f: s1-blocks) instead of 3 --
// fewer interleaved DRAM streams per block, longer sequential runs.

#define ECHO_SCALE 22.8f
#define N_ROWS 8192.0f
#define NY_BLOCKS 1024
#define NEF_BLOCKS 2048

typedef float fx4 __attribute__((ext_vector_type(4)));

__global__ void init_out_kernel(float* out) {
    if (threadIdx.x < 2) out[threadIdx.x] = 0.0f;
}

__device__ __forceinline__ fx4 ldnt(const fx4* p) {
    return __builtin_nontemporal_load(p);
}

__device__ __forceinline__ float pl0_4(const fx4& v, float inv_mu) {
    return fminf(fabsf(v.x) * inv_mu, 1.0f)
         + fminf(fabsf(v.y) * inv_mu, 1.0f)
         + fminf(fabsf(v.z) * inv_mu, 1.0f)
         + fminf(fabsf(v.w) * inv_mu, 1.0f);
}

__device__ __forceinline__ float l2_4(const fx4& e, const fx4& ff, float inv_echo) {
    float dx = e.x * inv_echo - ff.x;
    float dy = e.y * inv_echo - ff.y;
    float dz = e.z * inv_echo - ff.z;
    float dw = e.w * inv_echo - ff.w;
    return dx * dx + dy * dy + dz * dz + dw * dw;
}

__global__ __launch_bounds__(256) void loss_split_kernel(
    const fx4* __restrict__ y,
    const fx4* __restrict__ ye,
    const fx4* __restrict__ f,
    const float* __restrict__ mu_ptr,
    float* __restrict__ out,
    long long n4)
{
    __shared__ float lred[4];
    const int bid = blockIdx.x;
    const int tid = threadIdx.x;
    const long long bs = 256;

    float s = 0.0f;      // this block's partial (s0 or s1 per role)
    int out_idx;

    if (bid < NY_BLOCKS) {
        // Role A: pseudo-l0 over y. Single sequential stream, 128KB panel.
        out_idx = 0;
        const float inv_mu = 1.0f / mu_ptr[0];
        const long long pb = (n4 + NY_BLOCKS - 1) / NY_BLOCKS;
        const long long start = (long long)bid * pb;
        long long end = start + pb; if (end > n4) end = n4;

        float sa = 0.0f, sb = 0.0f;
        long long i = start + tid;
        for (; i + bs < end; i += 2 * bs) {
            fx4 v0 = ldnt(&y[i]);
            fx4 v1 = ldnt(&y[i + bs]);
            sa += pl0_4(v0, inv_mu);
            sb += pl0_4(v1, inv_mu);
        }
        for (; i < end; i += bs) sa += pl0_4(ldnt(&y[i]), inv_mu);
        s = sa + sb;
    } else {
        // Role B: l2 over (ye, f). Two sequential streams, 64KB panels each.
        out_idx = 1;
        const float inv_echo = 1.0f / ECHO_SCALE;
        const int eb = bid - NY_BLOCKS;
        const long long pb = (n4 + NEF_BLOCKS - 1) / NEF_BLOCKS;
        const long long start = (long long)eb * pb;
        long long end = start + pb; if (end > n4) end = n4;

        float sa = 0.0f, sb = 0.0f;
        long long i = start + tid;
        for (; i + bs < end; i += 2 * bs) {
            fx4 e0 = ldnt(&ye[i]);
            fx4 e1 = ldnt(&ye[i + bs]);
            fx4 f0 = ldnt(&f[i]);
            fx4 f1 = ldnt(&f[i + bs]);
            sa += l2_4(e0, f0, inv_echo);
            sb += l2_4(e1, f1, inv_echo);
        }
        for (; i < end; i += bs) sa += l2_4(ldnt(&ye[i]), ldnt(&f[i]), inv_echo);
        s = sa + sb;
    }

    // wave-64 butterfly reduce
    #pragma unroll
    for (int off = 32; off > 0; off >>= 1)
        s += __shfl_down(s, off, 64);

    const int wave = tid >> 6;
    const int lane = tid & 63;
    if (lane == 0) lred[wave] = s;
    __syncthreads();

    if (tid == 0) {
        float t = (lred[0] + lred[1]) + (lred[2] + lred[3]);
        atomicAdd(&out[out_idx], t * (1.0f / N_ROWS));
    }
}

extern "C" void kernel_launch(void* const* d_in, const int* in_sizes, int n_in,
                              void* d_out, int out_size, void* d_ws, size_t ws_size,
                              hipStream_t stream) {
    const fx4* y  = (const fx4*)d_in[0];
    const fx4* ye = (const fx4*)d_in[1];
    const fx4* f  = (const fx4*)d_in[2];
    const float* mu  = (const float*)d_in[3];
    float* out = (float*)d_out;

    const long long n  = (long long)in_sizes[0];  // 8192*4096, divisible by 4
    const long long n4 = n / 4;

    init_out_kernel<<<1, 64, 0, stream>>>(out);

    loss_split_kernel<<<NY_BLOCKS + NEF_BLOCKS, 256, 0, stream>>>(
        y, ye, f, mu, out, n4);
}

// Round 8
// 84.221 us; speedup vs baseline: 1.2371x; 1.0384x over previous
//
#include <hip/hip_runtime.h>

// Two-scalar fused loss over 8192x4096 f32 arrays:
//   out[0] = sum( min(|y|/mu, 1) ) / 8192
//   out[1] = sum( (y_echo/22.8 - f)^2 ) / 8192
// Memory-bound pure-read reduction: 3 arrays x 134MB, 8B written.
// Ceiling model (R7): CU-side read-return fabric ~8 B/cyc/CU -> ~4.9 TB/s;
// L3-hit-only replays measured 4.96 TB/s. We're at 4.6. This round: deepen
// per-thread MLP (role A: 4 loads in flight, role B: 8) to overlap HBM miss
// latency with the return stream. Structure: role-split panels + nt loads.

#define ECHO_SCALE 22.8f
#define N_ROWS 8192.0f
#define NY_BLOCKS 1024
#define NEF_BLOCKS 2048

typedef float fx4 __attribute__((ext_vector_type(4)));

__global__ void init_out_kernel(float* out) {
    if (threadIdx.x < 2) out[threadIdx.x] = 0.0f;
}

__device__ __forceinline__ fx4 ldnt(const fx4* p) {
    return __builtin_nontemporal_load(p);
}

__device__ __forceinline__ float pl0_4(const fx4& v, float inv_mu) {
    return fminf(fabsf(v.x) * inv_mu, 1.0f)
         + fminf(fabsf(v.y) * inv_mu, 1.0f)
         + fminf(fabsf(v.z) * inv_mu, 1.0f)
         + fminf(fabsf(v.w) * inv_mu, 1.0f);
}

__device__ __forceinline__ float l2_4(const fx4& e, const fx4& ff, float inv_echo) {
    float dx = e.x * inv_echo - ff.x;
    float dy = e.y * inv_echo - ff.y;
    float dz = e.z * inv_echo - ff.z;
    float dw = e.w * inv_echo - ff.w;
    return dx * dx + dy * dy + dz * dz + dw * dw;
}

__global__ __launch_bounds__(256) void loss_split_kernel(
    const fx4* __restrict__ y,
    const fx4* __restrict__ ye,
    const fx4* __restrict__ f,
    const float* __restrict__ mu_ptr,
    float* __restrict__ out,
    long long n4)
{
    __shared__ float lred[4];
    const int bid = blockIdx.x;
    const int tid = threadIdx.x;
    const long long bs = 256;

    float s = 0.0f;
    int out_idx;

    if (bid < NY_BLOCKS) {
        // Role A: pseudo-l0 over y. 1 sequential stream, 128KB panel.
        out_idx = 0;
        const float inv_mu = 1.0f / mu_ptr[0];
        const long long pb = (n4 + NY_BLOCKS - 1) / NY_BLOCKS;
        const long long start = (long long)bid * pb;
        long long end = start + pb; if (end > n4) end = n4;

        float sa = 0.0f, sb = 0.0f, sc = 0.0f, sd = 0.0f;
        long long i = start + tid;
        for (; i + 3 * bs < end; i += 4 * bs) {
            fx4 v0 = ldnt(&y[i]);
            fx4 v1 = ldnt(&y[i + bs]);
            fx4 v2 = ldnt(&y[i + 2 * bs]);
            fx4 v3 = ldnt(&y[i + 3 * bs]);
            sa += pl0_4(v0, inv_mu);
            sb += pl0_4(v1, inv_mu);
            sc += pl0_4(v2, inv_mu);
            sd += pl0_4(v3, inv_mu);
        }
        for (; i < end; i += bs) sa += pl0_4(ldnt(&y[i]), inv_mu);
        s = (sa + sb) + (sc + sd);
    } else {
        // Role B: l2 over (ye, f). 2 sequential streams, 64KB panels each.
        out_idx = 1;
        const float inv_echo = 1.0f / ECHO_SCALE;
        const int eb = bid - NY_BLOCKS;
        const long long pb = (n4 + NEF_BLOCKS - 1) / NEF_BLOCKS;
        const long long start = (long long)eb * pb;
        long long end = start + pb; if (end > n4) end = n4;

        float sa = 0.0f, sb = 0.0f, sc = 0.0f, sd = 0.0f;
        long long i = start + tid;
        for (; i + 3 * bs < end; i += 4 * bs) {
            fx4 e0 = ldnt(&ye[i]);
            fx4 e1 = ldnt(&ye[i + bs]);
            fx4 e2 = ldnt(&ye[i + 2 * bs]);
            fx4 e3 = ldnt(&ye[i + 3 * bs]);
            fx4 f0 = ldnt(&f[i]);
            fx4 f1 = ldnt(&f[i + bs]);
            fx4 f2 = ldnt(&f[i + 2 * bs]);
            fx4 f3 = ldnt(&f[i + 3 * bs]);
            sa += l2_4(e0, f0, inv_echo);
            sb += l2_4(e1, f1, inv_echo);
            sc += l2_4(e2, f2, inv_echo);
            sd += l2_4(e3, f3, inv_echo);
        }
        for (; i < end; i += bs) sa += l2_4(ldnt(&ye[i]), ldnt(&f[i]), inv_echo);
        s = (sa + sb) + (sc + sd);
    }

    // wave-64 butterfly reduce
    #pragma unroll
    for (int off = 32; off > 0; off >>= 1)
        s += __shfl_down(s, off, 64);

    const int wave = tid >> 6;
    const int lane = tid & 63;
    if (lane == 0) lred[wave] = s;
    __syncthreads();

    if (tid == 0) {
        float t = (lred[0] + lred[1]) + (lred[2] + lred[3]);
        atomicAdd(&out[out_idx], t * (1.0f / N_ROWS));
    }
}

extern "C" void kernel_launch(void* const* d_in, const int* in_sizes, int n_in,
                              void* d_out, int out_size, void* d_ws, size_t ws_size,
                              hipStream_t stream) {
    const fx4* y  = (const fx4*)d_in[0];
    const fx4* ye = (const fx4*)d_in[1];
    const fx4* f  = (const fx4*)d_in[2];
    const float* mu  = (const float*)d_in[3];
    float* out = (float*)d_out;

    const long long n  = (long long)in_sizes[0];  // 8192*4096, divisible by 4
    const long long n4 = n / 4;

    init_out_kernel<<<1, 64, 0, stream>>>(out);

    loss_split_kernel<<<NY_BLOCKS + NEF_BLOCKS, 256, 0, stream>>>(
        y, ye, f, mu, out, n4);
}